// Round 1
// baseline (531.890 us; speedup 1.0000x reference)
//
#include <hip/hip_runtime.h>
#include <hip/hip_bf16.h>
#include <stdint.h>

typedef unsigned short u16;
typedef __bf16 v8bf __attribute__((ext_vector_type(8)));
typedef float f32x4 __attribute__((ext_vector_type(4)));

#define BATCH 2
#define NSEQ  2048
#define DIM_  2048
#define QH    16
#define KVH   4
#define HD    128
#define KVDIM 512
#define MROWS (BATCH*NSEQ)

__device__ __forceinline__ u16 f2bf(float f) {
  uint32_t u = __builtin_bit_cast(uint32_t, f);
  u += 0x7FFFu + ((u >> 16) & 1u);
  return (u16)(u >> 16);
}
__device__ __forceinline__ float bf2f(u16 h) {
  uint32_t u = ((uint32_t)h) << 16;
  return __builtin_bit_cast(float, u);
}
__device__ __forceinline__ void gload_lds16(const void* g, void* l) {
  __builtin_amdgcn_global_load_lds((const __attribute__((address_space(1))) void*)g,
                                   (__attribute__((address_space(3))) void*)l, 16, 0, 0);
}

// ---------------- fp32 -> bf16 convert (vectorized) ----------------
__global__ void k_f32_to_bf16(const float* __restrict__ in, u16* __restrict__ out, int n) {
  int i = (blockIdx.x * 256 + threadIdx.x) * 4;
  if (i + 3 < n) {
    float4 v = *(const float4*)(in + i);
    ushort4 o;
    o.x = f2bf(v.x); o.y = f2bf(v.y); o.z = f2bf(v.z); o.w = f2bf(v.w);
    *(ushort4*)(out + i) = o;
  }
}

// ---------------- RoPE cos/sin table: [NSEQ][64] ----------------
__global__ void k_rope_table(float* __restrict__ tc, float* __restrict__ ts) {
  int idx = blockIdx.x * 256 + threadIdx.x;
  if (idx < NSEQ * 64) {
    int t = idx >> 6, i = idx & 63;
    float inv = powf(10000.0f, -(float)i / 64.0f);
    float ang = (float)t * inv;
    tc[idx] = cosf(ang);
    ts[idx] = sinf(ang);
  }
}

// ---------------- in-place RoPE on (MROWS, heads*128) bf16 ----------------
__global__ void k_rope(u16* __restrict__ x, const float* __restrict__ tc,
                       const float* __restrict__ ts, int heads) {
  int idx = blockIdx.x * 256 + threadIdx.x;
  int total = MROWS * heads * 64;
  if (idx >= total) return;
  int i = idx & 63;
  int h = (idx >> 6) % heads;
  int row = idx / (heads * 64);
  int t = row & (NSEQ - 1);
  size_t base = (size_t)row * heads * 128 + h * 128 + 2 * i;
  uint32_t pr = *(const uint32_t*)(x + base);
  float xr = bf2f((u16)(pr & 0xFFFFu));
  float xi = bf2f((u16)(pr >> 16));
  float c = tc[t * 64 + i], s = ts[t * 64 + i];
  float yr = xr * c - xi * s;
  float yi = xr * s + xi * c;
  uint32_t po = (uint32_t)f2bf(yr) | ((uint32_t)f2bf(yi) << 16);
  *(uint32_t*)(x + base) = po;
}

// ---------------- V transpose: (MROWS,512) -> (B,KVH,128,NSEQ) ----------------
__global__ void k_transpose_v(const u16* __restrict__ vp, u16* __restrict__ vt) {
  size_t idx = (size_t)blockIdx.x * 256 + threadIdx.x;
  if (idx >= (size_t)BATCH * KVH * HD * NSEQ) return;
  int n = (int)(idx & (NSEQ - 1));
  int d = (int)((idx >> 11) & (HD - 1));
  int h = (int)((idx >> 18) & (KVH - 1));
  int b = (int)(idx >> 20);
  vt[idx] = vp[(size_t)(b * NSEQ + n) * KVDIM + h * HD + d];
}

// ---------------- bf16 GEMM: C(M,N) = A(M,K) @ B(N,K)^T + bias ----------------
// m97 structure: 128x128 tile, BK=32, 4 waves (2x2 of 64x64), global_load_lds w=16.
template <typename OT>
__global__ __launch_bounds__(256) void k_gemm_bt(const u16* __restrict__ A, const u16* __restrict__ B,
                                                 const float* __restrict__ bias, OT* __restrict__ C,
                                                 int M, int N, int K) {
  __shared__ __align__(16) u16 As[128 * 32];
  __shared__ __align__(16) u16 Bs[128 * 32];
  int tid = threadIdx.x;
  int l = tid & 63, w = tid >> 6;
  int lg = l >> 4, lr = l & 15;
  int wr = w >> 1, wc = w & 1;
  int bm = blockIdx.x, bn = blockIdx.y;

  int srow = tid >> 2;          // 0..63
  int scol = (tid & 3) * 16;    // byte within 64B K-chunk

  const char* Ab = (const char*)A + ((size_t)(bm * 128 + srow) * K) * 2 + scol;
  const char* Bb = (const char*)B + ((size_t)(bn * 128 + srow) * K) * 2 + scol;
  char* AsB = (char*)As;
  char* BsB = (char*)Bs;

  f32x4 acc[4][4] = {};
  int ksteps = K >> 5;
  for (int kt = 0; kt < ksteps; ++kt) {
    __syncthreads();
    size_t koff = (size_t)kt * 64;
    gload_lds16(Ab + koff, AsB + srow * 64 + scol);
    gload_lds16(Ab + koff + (size_t)64 * K * 2, AsB + (srow + 64) * 64 + scol);
    gload_lds16(Bb + koff, BsB + srow * 64 + scol);
    gload_lds16(Bb + koff + (size_t)64 * K * 2, BsB + (srow + 64) * 64 + scol);
    __syncthreads();

    v8bf af[4], bf[4];
#pragma unroll
    for (int mi = 0; mi < 4; ++mi)
      af[mi] = *(const v8bf*)(AsB + (wr * 64 + mi * 16 + lr) * 64 + lg * 16);
#pragma unroll
    for (int ni = 0; ni < 4; ++ni)
      bf[ni] = *(const v8bf*)(BsB + (wc * 64 + ni * 16 + lr) * 64 + lg * 16);
#pragma unroll
    for (int mi = 0; mi < 4; ++mi)
#pragma unroll
      for (int ni = 0; ni < 4; ++ni)
        acc[mi][ni] = __builtin_amdgcn_mfma_f32_16x16x32_bf16(af[mi], bf[ni], acc[mi][ni], 0, 0, 0);
  }

#pragma unroll
  for (int mi = 0; mi < 4; ++mi)
#pragma unroll
    for (int ni = 0; ni < 4; ++ni) {
      int grow0 = bm * 128 + wr * 64 + mi * 16 + lg * 4;
      int gcol = bn * 128 + wc * 64 + ni * 16 + lr;
      float bsv = bias[gcol];
#pragma unroll
      for (int r = 0; r < 4; ++r) {
        float v = acc[mi][ni][r] + bsv;
        size_t off = (size_t)(grow0 + r) * N + gcol;
        if constexpr (sizeof(OT) == 2) C[off] = f2bf(v);
        else C[off] = v;
      }
    }
}

// ---------------- flash attention ----------------
// q: (B,N,16*128) post-RoPE bf16 ; k: (B,N,4*128) post-RoPE bf16 ; vt: (B,KVH,128,N) bf16
// out: (B,N,2048) bf16.  grid(N/64, QH, B), 256 thr = 4 waves x 16 q-rows, KVBLK=64.
__global__ __launch_bounds__(256) void k_attn(const u16* __restrict__ q, const u16* __restrict__ k,
                                              const u16* __restrict__ vt, u16* __restrict__ out) {
  __shared__ __align__(16) u16 Ks[64 * 128];   // rows=kv, 256B rows, XOR-swizzled
  __shared__ __align__(16) u16 Vs[128 * 64];   // rows=d,  128B rows, XOR-swizzled
  __shared__ __align__(16) u16 Ps[4][16 * 72]; // per-wave P transpose, pad 64->72

  int tid = threadIdx.x;
  int l = tid & 63, w = tid >> 6;
  int lg = l >> 4, lr = l & 15;
  int qt = blockIdx.x, h = blockIdx.y, b = blockIdx.z;
  int kvh = h >> 2;
  const float scale = 0.08838834764831845f; // 1/sqrt(128)

  int q0 = qt * 64 + w * 16;
  const char* qb = (const char*)q + ((size_t)(b * NSEQ + q0 + lr) * DIM_ + h * HD) * 2;
  v8bf qf[4];
#pragma unroll
  for (int kk = 0; kk < 4; ++kk) qf[kk] = *(const v8bf*)(qb + kk * 64 + lg * 16);

  f32x4 od[8] = {};
  float mrow[4], lrow[4];
#pragma unroll
  for (int r = 0; r < 4; ++r) { mrow[r] = -INFINITY; lrow[r] = 0.f; }

  const char* kbase = (const char*)k + ((size_t)(b * NSEQ) * KVDIM + kvh * HD) * 2;
  const char* vbase = (const char*)vt + ((size_t)(b * KVH + kvh) * HD) * NSEQ * 2;
  char* KsB = (char*)Ks;
  char* VsB = (char*)Vs;

  int srowK = tid >> 4;          // 16 rows / issue
  int scolK = (tid & 15) * 16;   // 0..240
  int srowV = tid >> 3;          // 32 rows / issue
  int scolV = (tid & 7) * 16;    // 0..112

  for (int kt = 0; kt <= qt; ++kt) {
    __syncthreads();
#pragma unroll
    for (int i = 0; i < 4; ++i) { // K tile: 64 rows x 256B
      int row = i * 16 + srowK;
      *(v8bf*)(KsB + row * 256 + (scolK ^ ((row & 7) << 4))) =
          *(const v8bf*)(kbase + (size_t)(kt * 64 + row) * KVDIM * 2 + scolK);
    }
#pragma unroll
    for (int i = 0; i < 4; ++i) { // V tile: 128 d-rows x 128B
      int row = i * 32 + srowV;
      *(v8bf*)(VsB + row * 128 + (scolV ^ ((row & 7) << 4))) =
          *(const v8bf*)(vbase + (size_t)row * NSEQ * 2 + (size_t)(kt * 64) * 2 + scolV);
    }
    __syncthreads();

    // S = Q K^T (4 tiles of 16 kv cols)
    f32x4 st[4];
#pragma unroll
    for (int nt = 0; nt < 4; ++nt) {
      f32x4 a = {};
#pragma unroll
      for (int kk = 0; kk < 4; ++kk) {
        int krow = nt * 16 + lr;
        v8bf kf = *(const v8bf*)(KsB + krow * 256 + ((kk * 64 + lg * 16) ^ ((krow & 7) << 4)));
        a = __builtin_amdgcn_mfma_f32_16x16x32_bf16(qf[kk], kf, a, 0, 0, 0);
      }
      st[nt] = a;
    }

    // online softmax; lane owns col lr of rows lg*4+r
    float p[4][4];
#pragma unroll
    for (int r = 0; r < 4; ++r) {
      int qrow = q0 + lg * 4 + r;
      float mx = -1e30f;
#pragma unroll
      for (int nt = 0; nt < 4; ++nt) {
        int scol = kt * 64 + nt * 16 + lr;
        float v = st[nt][r] * scale;
        if (scol > qrow) v = -1e30f;
        st[nt][r] = v;
        mx = fmaxf(mx, v);
      }
#pragma unroll
      for (int off = 1; off < 16; off <<= 1) mx = fmaxf(mx, __shfl_xor(mx, off));
      float nm = fmaxf(mrow[r], mx);
      float corr = __expf(mrow[r] - nm);
      mrow[r] = nm;
      float rs = 0.f;
#pragma unroll
      for (int nt = 0; nt < 4; ++nt) {
        float pv = __expf(st[nt][r] - nm);
        p[nt][r] = pv;
        rs += pv;
      }
#pragma unroll
      for (int off = 1; off < 16; off <<= 1) rs += __shfl_xor(rs, off);
      lrow[r] = lrow[r] * corr + rs;
#pragma unroll
      for (int dt = 0; dt < 8; ++dt) od[dt][r] *= corr;
    }

    // P -> LDS (transpose for A-operand)
#pragma unroll
    for (int nt = 0; nt < 4; ++nt)
#pragma unroll
      for (int r = 0; r < 4; ++r)
        Ps[w][(lg * 4 + r) * 72 + nt * 16 + lr] = f2bf(p[nt][r]);
    asm volatile("s_waitcnt lgkmcnt(0)" ::: "memory");
    __builtin_amdgcn_sched_barrier(0);

    // O += P V
#pragma unroll
    for (int kc = 0; kc < 2; ++kc) {
      v8bf pf = *(const v8bf*)((const char*)&Ps[w][0] + lr * 144 + kc * 64 + lg * 16);
#pragma unroll
      for (int dt = 0; dt < 8; ++dt) {
        int vrow = dt * 16 + lr;
        v8bf vf = *(const v8bf*)(VsB + vrow * 128 + ((kc * 64 + lg * 16) ^ ((vrow & 7) << 4)));
        od[dt] = __builtin_amdgcn_mfma_f32_16x16x32_bf16(pf, vf, od[dt], 0, 0, 0);
      }
    }
  }

  // normalize + write (B,N,2048) bf16
#pragma unroll
  for (int r = 0; r < 4; ++r) {
    int qrow = q0 + lg * 4 + r;
    float inv = 1.0f / lrow[r];
    char* ob = (char*)out + ((size_t)(b * NSEQ + qrow) * DIM_ + h * HD) * 2;
#pragma unroll
    for (int dt = 0; dt < 8; ++dt)
      *(u16*)(ob + (dt * 16 + lr) * 2) = f2bf(od[dt][r] * inv);
  }
}

// ---------------- launch ----------------
extern "C" void kernel_launch(void* const* d_in, const int* in_sizes, int n_in,
                              void* d_out, int out_size, void* d_ws, size_t ws_size,
                              hipStream_t stream) {
  const float* query = (const float*)d_in[0];
  const float* key_ = (const float*)d_in[1];
  const float* value = (const float*)d_in[2];
  const float* Wq = (const float*)d_in[3];
  const float* bq = (const float*)d_in[4];
  const float* Wk = (const float*)d_in[5];
  const float* bk = (const float*)d_in[6];
  const float* Wv = (const float*)d_in[7];
  const float* bv = (const float*)d_in[8];
  const float* Wo = (const float*)d_in[9];
  const float* bo = (const float*)d_in[10];

  char* ws = (char*)d_ws;
  u16* wq_bf = (u16*)(ws + 0);           // 8,388,608
  u16* wk_bf = (u16*)(ws + 8388608);     // 2,097,152
  u16* wv_bf = (u16*)(ws + 10485760);    // 2,097,152
  u16* wo_bf = (u16*)(ws + 12582912);    // 8,388,608
  float* tabc = (float*)(ws + 20971520); // 524,288
  float* tabs = (float*)(ws + 21495808); // 524,288
  u16* xq = (u16*)(ws + 22020096);       // 16,777,216
  u16* xk = (u16*)(ws + 38797312);       // 16,777,216
  u16* xv = (u16*)(ws + 55574528);       // 16,777,216
  u16* qproj = (u16*)(ws + 72351744);    // 16,777,216
  u16* kproj = (u16*)(ws + 89128960);    // 4,194,304
  u16* vproj = (u16*)(ws + 93323264);    // 4,194,304  (total 97,517,568)
  u16* vt = xq;       // xq dead after qproj GEMM
  u16* attno = xk;    // xk dead after kproj GEMM

  k_f32_to_bf16<<<dim3(DIM_ * DIM_ / 1024), 256, 0, stream>>>(Wq, wq_bf, DIM_ * DIM_);
  k_f32_to_bf16<<<dim3(KVDIM * DIM_ / 1024), 256, 0, stream>>>(Wk, wk_bf, KVDIM * DIM_);
  k_f32_to_bf16<<<dim3(KVDIM * DIM_ / 1024), 256, 0, stream>>>(Wv, wv_bf, KVDIM * DIM_);
  k_f32_to_bf16<<<dim3(DIM_ * DIM_ / 1024), 256, 0, stream>>>(Wo, wo_bf, DIM_ * DIM_);
  k_f32_to_bf16<<<dim3(MROWS * DIM_ / 1024), 256, 0, stream>>>(query, xq, MROWS * DIM_);
  k_f32_to_bf16<<<dim3(MROWS * DIM_ / 1024), 256, 0, stream>>>(key_, xk, MROWS * DIM_);
  k_f32_to_bf16<<<dim3(MROWS * DIM_ / 1024), 256, 0, stream>>>(value, xv, MROWS * DIM_);
  k_rope_table<<<dim3(NSEQ * 64 / 256), 256, 0, stream>>>(tabc, tabs);

  k_gemm_bt<u16><<<dim3(MROWS / 128, DIM_ / 128), 256, 0, stream>>>(xq, wq_bf, bq, qproj, MROWS, DIM_, DIM_);
  k_gemm_bt<u16><<<dim3(MROWS / 128, KVDIM / 128), 256, 0, stream>>>(xk, wk_bf, bk, kproj, MROWS, KVDIM, DIM_);
  k_gemm_bt<u16><<<dim3(MROWS / 128, KVDIM / 128), 256, 0, stream>>>(xv, wv_bf, bv, vproj, MROWS, KVDIM, DIM_);

  k_rope<<<dim3(MROWS * QH * 64 / 256), 256, 0, stream>>>(qproj, tabc, tabs, QH);
  k_rope<<<dim3(MROWS * KVH * 64 / 256), 256, 0, stream>>>(kproj, tabc, tabs, KVH);
  k_transpose_v<<<dim3((BATCH * KVH * HD * NSEQ) / 256), 256, 0, stream>>>(vproj, vt);

  k_attn<<<dim3(NSEQ / 64, QH, BATCH), 256, 0, stream>>>(qproj, kproj, vt, attno);

  k_gemm_bt<float><<<dim3(MROWS / 128, DIM_ / 128), 256, 0, stream>>>(attno, wo_bf, bo, (float*)d_out, MROWS, DIM_, DIM_);
}

// Round 2
// 359.633 us; speedup vs baseline: 1.4790x; 1.4790x over previous
//
#include <hip/hip_runtime.h>
#include <hip/hip_bf16.h>
#include <stdint.h>

typedef unsigned short u16;
typedef __bf16 v8bf __attribute__((ext_vector_type(8)));
typedef float f32x4 __attribute__((ext_vector_type(4)));

#define BATCH 2
#define NSEQ  2048
#define DIM_  2048
#define QH    16
#define KVH   4
#define HD    128
#define KVDIM 512
#define MROWS (BATCH*NSEQ)

__device__ __forceinline__ u16 f2bf(float f) {
  uint32_t u = __builtin_bit_cast(uint32_t, f);
  u += 0x7FFFu + ((u >> 16) & 1u);
  return (u16)(u >> 16);
}
__device__ __forceinline__ float bf2f(u16 h) {
  uint32_t u = ((uint32_t)h) << 16;
  return __builtin_bit_cast(float, u);
}
__device__ __forceinline__ void gload_lds16(const void* g, void* l) {
  __builtin_amdgcn_global_load_lds((const __attribute__((address_space(1))) void*)g,
                                   (__attribute__((address_space(3))) void*)l, 16, 0, 0);
}

// ---------------- fp32 -> bf16 convert (vectorized) ----------------
__global__ void k_f32_to_bf16(const float* __restrict__ in, u16* __restrict__ out, int n) {
  int i = (blockIdx.x * 256 + threadIdx.x) * 4;
  if (i + 3 < n) {
    float4 v = *(const float4*)(in + i);
    ushort4 o;
    o.x = f2bf(v.x); o.y = f2bf(v.y); o.z = f2bf(v.z); o.w = f2bf(v.w);
    *(ushort4*)(out + i) = o;
  }
}

// ---------------- RoPE cos/sin table: [NSEQ][64] ----------------
__global__ void k_rope_table(float* __restrict__ tc, float* __restrict__ ts) {
  int idx = blockIdx.x * 256 + threadIdx.x;
  if (idx < NSEQ * 64) {
    int t = idx >> 6, i = idx & 63;
    float inv = powf(10000.0f, -(float)i / 64.0f);
    float ang = (float)t * inv;
    tc[idx] = cosf(ang);
    ts[idx] = sinf(ang);
  }
}

// ---------------- in-place RoPE on (MROWS, heads*128) bf16 ----------------
__global__ void k_rope(u16* __restrict__ x, const float* __restrict__ tc,
                       const float* __restrict__ ts, int heads) {
  int idx = blockIdx.x * 256 + threadIdx.x;
  int total = MROWS * heads * 64;
  if (idx >= total) return;
  int i = idx & 63;
  int h = (idx >> 6) % heads;
  int row = idx / (heads * 64);
  int t = row & (NSEQ - 1);
  size_t base = (size_t)row * heads * 128 + h * 128 + 2 * i;
  uint32_t pr = *(const uint32_t*)(x + base);
  float xr = bf2f((u16)(pr & 0xFFFFu));
  float xi = bf2f((u16)(pr >> 16));
  float c = tc[t * 64 + i], s = ts[t * 64 + i];
  float yr = xr * c - xi * s;
  float yi = xr * s + xi * c;
  uint32_t po = (uint32_t)f2bf(yr) | ((uint32_t)f2bf(yi) << 16);
  *(uint32_t*)(x + base) = po;
}

// ---------------- V transpose: (MROWS,512) -> (B,KVH,128,NSEQ) ----------------
__global__ void k_transpose_v(const u16* __restrict__ vp, u16* __restrict__ vt) {
  size_t idx = (size_t)blockIdx.x * 256 + threadIdx.x;
  if (idx >= (size_t)BATCH * KVH * HD * NSEQ) return;
  int n = (int)(idx & (NSEQ - 1));
  int d = (int)((idx >> 11) & (HD - 1));
  int h = (int)((idx >> 18) & (KVH - 1));
  int b = (int)(idx >> 20);
  vt[idx] = vp[(size_t)(b * NSEQ + n) * KVDIM + h * HD + d];
}

// ---------------- bf16 GEMM: C(M,N) = A(M,K) @ B(N,K)^T + bias ----------------
template <typename OT>
__global__ __launch_bounds__(256) void k_gemm_bt(const u16* __restrict__ A, const u16* __restrict__ B,
                                                 const float* __restrict__ bias, OT* __restrict__ C,
                                                 int M, int N, int K) {
  __shared__ __align__(16) u16 As[128 * 32];
  __shared__ __align__(16) u16 Bs[128 * 32];
  int tid = threadIdx.x;
  int l = tid & 63, w = tid >> 6;
  int lg = l >> 4, lr = l & 15;
  int wr = w >> 1, wc = w & 1;
  int bm = blockIdx.x, bn = blockIdx.y;

  int srow = tid >> 2;
  int scol = (tid & 3) * 16;

  const char* Ab = (const char*)A + ((size_t)(bm * 128 + srow) * K) * 2 + scol;
  const char* Bb = (const char*)B + ((size_t)(bn * 128 + srow) * K) * 2 + scol;
  char* AsB = (char*)As;
  char* BsB = (char*)Bs;

  f32x4 acc[4][4] = {};
  int ksteps = K >> 5;
  for (int kt = 0; kt < ksteps; ++kt) {
    __syncthreads();
    size_t koff = (size_t)kt * 64;
    gload_lds16(Ab + koff, AsB + srow * 64 + scol);
    gload_lds16(Ab + koff + (size_t)64 * K * 2, AsB + (srow + 64) * 64 + scol);
    gload_lds16(Bb + koff, BsB + srow * 64 + scol);
    gload_lds16(Bb + koff + (size_t)64 * K * 2, BsB + (srow + 64) * 64 + scol);
    __syncthreads();

    v8bf af[4], bfr[4];
#pragma unroll
    for (int mi = 0; mi < 4; ++mi)
      af[mi] = *(const v8bf*)(AsB + (wr * 64 + mi * 16 + lr) * 64 + lg * 16);
#pragma unroll
    for (int ni = 0; ni < 4; ++ni)
      bfr[ni] = *(const v8bf*)(BsB + (wc * 64 + ni * 16 + lr) * 64 + lg * 16);
#pragma unroll
    for (int mi = 0; mi < 4; ++mi)
#pragma unroll
      for (int ni = 0; ni < 4; ++ni)
        acc[mi][ni] = __builtin_amdgcn_mfma_f32_16x16x32_bf16(af[mi], bfr[ni], acc[mi][ni], 0, 0, 0);
  }

#pragma unroll
  for (int mi = 0; mi < 4; ++mi)
#pragma unroll
    for (int ni = 0; ni < 4; ++ni) {
      int grow0 = bm * 128 + wr * 64 + mi * 16 + lg * 4;
      int gcol = bn * 128 + wc * 64 + ni * 16 + lr;
      float bsv = bias[gcol];
#pragma unroll
      for (int r = 0; r < 4; ++r) {
        float v = acc[mi][ni][r] + bsv;
        size_t off = (size_t)(grow0 + r) * N + gcol;
        if constexpr (sizeof(OT) == 2) C[off] = f2bf(v);
        else C[off] = v;
      }
    }
}

// ---------------- flash attention v2 ----------------
// Complement-paired causal tiles: block does q-tiles qt and 31-qt -> uniform 33 KV-iters.
// 4 waves x 16 q-rows = 64-row q-tile; KVBLK=64; T14 reg-prefetch of next K/V tile.
__global__ __launch_bounds__(256, 2) void k_attn(const u16* __restrict__ q, const u16* __restrict__ k,
                                                 const u16* __restrict__ vt, u16* __restrict__ out) {
  __shared__ __align__(16) u16 Ks[64 * 128];   // rows=kv, 256B rows, XOR-swizzled
  __shared__ __align__(16) u16 Vs[128 * 64];   // rows=d,  128B rows, XOR-swizzled
  __shared__ __align__(16) u16 Ps[4][16 * 64]; // per-wave P, [16 rows][128B], XOR-swizzled

  int tid = threadIdx.x;
  int l = tid & 63, w = tid >> 6;
  int lg = l >> 4, lr = l & 15;
  int h = blockIdx.y, b = blockIdx.z;
  int kvh = h >> 2;
  const float scale = 0.08838834764831845f; // 1/sqrt(128)

  const char* kbase = (const char*)k + ((size_t)(b * NSEQ) * KVDIM + kvh * HD) * 2;
  const char* vbase = (const char*)vt + ((size_t)(b * KVH + kvh) * HD) * NSEQ * 2;
  char* KsB = (char*)Ks;
  char* VsB = (char*)Vs;
  char* PsB = (char*)&Ps[w][0];

  // staging geometry (256 threads)
  int krow0 = tid >> 4;          // 0..15 (x4 rows via i)
  int kcol = (tid & 15) * 16;    // 0..240
  int vrow0 = tid >> 3;          // 0..31 (x4 rows via i)
  int vcol = (tid & 7) * 16;     // 0..112

  v8bf kr[4], vr[4];

#define LOADKV(KT)                                                                          \
  {                                                                                         \
    _Pragma("unroll") for (int i = 0; i < 4; ++i)                                           \
        kr[i] = *(const v8bf*)(kbase + (size_t)((KT) * 64 + krow0 + i * 16) * KVDIM * 2 + kcol); \
    _Pragma("unroll") for (int i = 0; i < 4; ++i)                                           \
        vr[i] = *(const v8bf*)(vbase + (size_t)(vrow0 + i * 32) * NSEQ * 2 + (size_t)(KT) * 128 + vcol); \
  }
#define WRITEKV()                                                                           \
  {                                                                                         \
    _Pragma("unroll") for (int i = 0; i < 4; ++i) {                                         \
      int row = krow0 + i * 16;                                                             \
      *(v8bf*)(KsB + row * 256 + (kcol ^ ((row & 7) << 4))) = kr[i];                        \
    }                                                                                       \
    _Pragma("unroll") for (int i = 0; i < 4; ++i) {                                         \
      int row = vrow0 + i * 32;                                                             \
      *(v8bf*)(VsB + row * 128 + (vcol ^ ((row & 7) << 4))) = vr[i];                        \
    }                                                                                       \
  }

  for (int pass = 0; pass < 2; ++pass) {
    int qt = pass ? (31 - blockIdx.x) : blockIdx.x;
    int q0 = qt * 64 + w * 16;

    // Q fragment for this tile
    const char* qb = (const char*)q + ((size_t)(b * NSEQ + q0 + lr) * DIM_ + h * HD) * 2;
    v8bf qf[4];
#pragma unroll
    for (int kk = 0; kk < 4; ++kk) qf[kk] = *(const v8bf*)(qb + kk * 64 + lg * 16);

    f32x4 od[8] = {};
    float mrow[4], lrow[4];
#pragma unroll
    for (int r = 0; r < 4; ++r) { mrow[r] = -INFINITY; lrow[r] = 0.f; }

    int ktmax = qt;
    LOADKV(0);
    WRITEKV();
    __syncthreads();

    for (int kt = 0; kt <= ktmax; ++kt) {
      if (kt < ktmax) LOADKV(kt + 1);  // in flight during compute

      // S = Q K^T
      f32x4 st[4];
      __builtin_amdgcn_s_setprio(1);
#pragma unroll
      for (int nt = 0; nt < 4; ++nt) {
        f32x4 a = {};
#pragma unroll
        for (int kk = 0; kk < 4; ++kk) {
          int krow = nt * 16 + lr;
          v8bf kf = *(const v8bf*)(KsB + krow * 256 + ((kk * 64 + lg * 16) ^ ((krow & 7) << 4)));
          a = __builtin_amdgcn_mfma_f32_16x16x32_bf16(qf[kk], kf, a, 0, 0, 0);
        }
        st[nt] = a;
      }
      __builtin_amdgcn_s_setprio(0);

      // online softmax; lane owns col lr of rows lg*4+r
      float p[4][4];
#pragma unroll
      for (int r = 0; r < 4; ++r) {
        int qrow = q0 + lg * 4 + r;
        float mx = -1e30f;
#pragma unroll
        for (int nt = 0; nt < 4; ++nt) {
          int scol = kt * 64 + nt * 16 + lr;
          float v = st[nt][r] * scale;
          if (scol > qrow) v = -1e30f;
          st[nt][r] = v;
          mx = fmaxf(mx, v);
        }
#pragma unroll
        for (int off = 1; off < 16; off <<= 1) mx = fmaxf(mx, __shfl_xor(mx, off));
        float nm = fmaxf(mrow[r], mx);
        float corr = __expf(mrow[r] - nm);
        mrow[r] = nm;
        float rs = 0.f;
#pragma unroll
        for (int nt = 0; nt < 4; ++nt) {
          float pv = __expf(st[nt][r] - nm);
          p[nt][r] = pv;
          rs += pv;
        }
#pragma unroll
        for (int off = 1; off < 16; off <<= 1) rs += __shfl_xor(rs, off);
        lrow[r] = lrow[r] * corr + rs;
#pragma unroll
        for (int dt = 0; dt < 8; ++dt) od[dt][r] *= corr;
      }

      // P -> LDS (swizzled [16][64] per wave)
#pragma unroll
      for (int nt = 0; nt < 4; ++nt)
#pragma unroll
        for (int r = 0; r < 4; ++r) {
          int row = lg * 4 + r;
          *(u16*)(PsB + row * 128 + ((nt * 32 + lr * 2) ^ ((row & 7) << 4))) = f2bf(p[nt][r]);
        }
      asm volatile("s_waitcnt lgkmcnt(0)" ::: "memory");
      __builtin_amdgcn_sched_barrier(0);

      // O += P V
      __builtin_amdgcn_s_setprio(1);
#pragma unroll
      for (int kc = 0; kc < 2; ++kc) {
        v8bf pf = *(const v8bf*)(PsB + lr * 128 + ((kc * 64 + lg * 16) ^ ((lr & 7) << 4)));
#pragma unroll
        for (int dt = 0; dt < 8; ++dt) {
          int vrow = dt * 16 + lr;
          v8bf vf = *(const v8bf*)(VsB + vrow * 128 + ((kc * 64 + lg * 16) ^ ((vrow & 7) << 4)));
          od[dt] = __builtin_amdgcn_mfma_f32_16x16x32_bf16(pf, vf, od[dt], 0, 0, 0);
        }
      }
      __builtin_amdgcn_s_setprio(0);

      __syncthreads();              // all reads of current tile done
      if (kt < ktmax) WRITEKV();    // vmcnt wait inserted by compiler
      __syncthreads();              // new tile visible
    }

    // normalize + write
#pragma unroll
    for (int r = 0; r < 4; ++r) {
      int qrow = q0 + lg * 4 + r;
      float inv = 1.0f / lrow[r];
      char* ob = (char*)out + ((size_t)(b * NSEQ + qrow) * DIM_ + h * HD) * 2;
#pragma unroll
      for (int dt = 0; dt < 8; ++dt)
        *(u16*)(ob + (dt * 16 + lr) * 2) = f2bf(od[dt][r] * inv);
    }
  }
#undef LOADKV
#undef WRITEKV
}

// ---------------- launch ----------------
extern "C" void kernel_launch(void* const* d_in, const int* in_sizes, int n_in,
                              void* d_out, int out_size, void* d_ws, size_t ws_size,
                              hipStream_t stream) {
  const float* query = (const float*)d_in[0];
  const float* key_ = (const float*)d_in[1];
  const float* value = (const float*)d_in[2];
  const float* Wq = (const float*)d_in[3];
  const float* bq = (const float*)d_in[4];
  const float* Wk = (const float*)d_in[5];
  const float* bk = (const float*)d_in[6];
  const float* Wv = (const float*)d_in[7];
  const float* bv = (const float*)d_in[8];
  const float* Wo = (const float*)d_in[9];
  const float* bo = (const float*)d_in[10];

  char* ws = (char*)d_ws;
  u16* wq_bf = (u16*)(ws + 0);
  u16* wk_bf = (u16*)(ws + 8388608);
  u16* wv_bf = (u16*)(ws + 10485760);
  u16* wo_bf = (u16*)(ws + 12582912);
  float* tabc = (float*)(ws + 20971520);
  float* tabs = (float*)(ws + 21495808);
  u16* xq = (u16*)(ws + 22020096);
  u16* xk = (u16*)(ws + 38797312);
  u16* xv = (u16*)(ws + 55574528);
  u16* qproj = (u16*)(ws + 72351744);
  u16* kproj = (u16*)(ws + 89128960);
  u16* vproj = (u16*)(ws + 93323264);
  u16* vt = xq;       // xq dead after qproj GEMM
  u16* attno = xk;    // xk dead after kproj GEMM

  k_f32_to_bf16<<<dim3(DIM_ * DIM_ / 1024), 256, 0, stream>>>(Wq, wq_bf, DIM_ * DIM_);
  k_f32_to_bf16<<<dim3(KVDIM * DIM_ / 1024), 256, 0, stream>>>(Wk, wk_bf, KVDIM * DIM_);
  k_f32_to_bf16<<<dim3(KVDIM * DIM_ / 1024), 256, 0, stream>>>(Wv, wv_bf, KVDIM * DIM_);
  k_f32_to_bf16<<<dim3(DIM_ * DIM_ / 1024), 256, 0, stream>>>(Wo, wo_bf, DIM_ * DIM_);
  k_f32_to_bf16<<<dim3(MROWS * DIM_ / 1024), 256, 0, stream>>>(query, xq, MROWS * DIM_);
  k_f32_to_bf16<<<dim3(MROWS * DIM_ / 1024), 256, 0, stream>>>(key_, xk, MROWS * DIM_);
  k_f32_to_bf16<<<dim3(MROWS * DIM_ / 1024), 256, 0, stream>>>(value, xv, MROWS * DIM_);
  k_rope_table<<<dim3(NSEQ * 64 / 256), 256, 0, stream>>>(tabc, tabs);

  k_gemm_bt<u16><<<dim3(MROWS / 128, DIM_ / 128), 256, 0, stream>>>(xq, wq_bf, bq, qproj, MROWS, DIM_, DIM_);
  k_gemm_bt<u16><<<dim3(MROWS / 128, KVDIM / 128), 256, 0, stream>>>(xk, wk_bf, bk, kproj, MROWS, KVDIM, DIM_);
  k_gemm_bt<u16><<<dim3(MROWS / 128, KVDIM / 128), 256, 0, stream>>>(xv, wv_bf, bv, vproj, MROWS, KVDIM, DIM_);

  k_rope<<<dim3(MROWS * QH * 64 / 256), 256, 0, stream>>>(qproj, tabc, tabs, QH);
  k_rope<<<dim3(MROWS * KVH * 64 / 256), 256, 0, stream>>>(kproj, tabc, tabs, KVH);
  k_transpose_v<<<dim3((BATCH * KVH * HD * NSEQ) / 256), 256, 0, stream>>>(vproj, vt);

  k_attn<<<dim3(NSEQ / 128, QH, BATCH), 256, 0, stream>>>(qproj, kproj, vt, attno);

  k_gemm_bt<float><<<dim3(MROWS / 128, DIM_ / 128), 256, 0, stream>>>(attno, wo_bf, bo, (float*)d_out, MROWS, DIM_, DIM_);
}

// Round 4
// 279.488 us; speedup vs baseline: 1.9031x; 1.2868x over previous
//
#include <hip/hip_runtime.h>
#include <hip/hip_bf16.h>
#include <stdint.h>

typedef unsigned short u16;
typedef __bf16 v8bf __attribute__((ext_vector_type(8)));
typedef float f32x4 __attribute__((ext_vector_type(4)));

#define BATCH 2
#define NSEQ  2048
#define DIM_  2048
#define QH    16
#define KVH   4
#define HD    128
#define KVDIM 512
#define QKVS  3072
#define MROWS (BATCH*NSEQ)

__device__ __forceinline__ u16 f2bf(float f) {
  uint32_t u = __builtin_bit_cast(uint32_t, f);
  u += 0x7FFFu + ((u >> 16) & 1u);
  return (u16)(u >> 16);
}
__device__ __forceinline__ float bf2f(u16 h) {
  uint32_t u = ((uint32_t)h) << 16;
  return __builtin_bit_cast(float, u);
}
__device__ __forceinline__ uint32_t cvt_pk_bf16(float lo, float hi) {
  uint32_t r;
  asm("v_cvt_pk_bf16_f32 %0, %1, %2" : "=v"(r) : "v"(lo), "v"(hi));
  return r;
}
__device__ __forceinline__ void gload_lds16(const void* g, void* l) {
  __builtin_amdgcn_global_load_lds((const __attribute__((address_space(1))) void*)g,
                                   (__attribute__((address_space(3))) void*)l, 16, 0, 0);
}

// ---------------- fp32 -> bf16 convert (vectorized) ----------------
__global__ void k_f32_to_bf16(const float* __restrict__ in, u16* __restrict__ out, int n) {
  int i = (blockIdx.x * 256 + threadIdx.x) * 4;
  if (i + 3 < n) {
    float4 v = *(const float4*)(in + i);
    ushort4 o;
    o.x = f2bf(v.x); o.y = f2bf(v.y); o.z = f2bf(v.z); o.w = f2bf(v.w);
    *(ushort4*)(out + i) = o;
  }
}

// ---------------- RoPE cos/sin table: [NSEQ][64] ----------------
__global__ void k_rope_table(float* __restrict__ tc, float* __restrict__ ts) {
  int idx = blockIdx.x * 256 + threadIdx.x;
  if (idx < NSEQ * 64) {
    int t = idx >> 6, i = idx & 63;
    float inv = powf(10000.0f, -(float)i / 64.0f);
    float ang = (float)t * inv;
    tc[idx] = cosf(ang);
    ts[idx] = sinf(ang);
  }
}

// ---------------- in-place RoPE on (MROWS, stride) bf16, heads*128 cols ----------------
__global__ void k_rope(u16* __restrict__ x, const float* __restrict__ tc,
                       const float* __restrict__ ts, int heads, int stride) {
  int idx = blockIdx.x * 256 + threadIdx.x;
  int total = MROWS * heads * 64;
  if (idx >= total) return;
  int i = idx & 63;
  int h = (idx >> 6) % heads;
  int row = idx / (heads * 64);
  int t = row & (NSEQ - 1);
  size_t base = (size_t)row * stride + h * 128 + 2 * i;
  uint32_t pr = *(const uint32_t*)(x + base);
  float xr = bf2f((u16)(pr & 0xFFFFu));
  float xi = bf2f((u16)(pr >> 16));
  float c = tc[t * 64 + i], s = ts[t * 64 + i];
  float yr = xr * c - xi * s;
  float yi = xr * s + xi * c;
  uint32_t po = (uint32_t)f2bf(yr) | ((uint32_t)f2bf(yi) << 16);
  *(uint32_t*)(x + base) = po;
}

// ---------------- V transpose: rows (MROWS, stride=QKVS) -> (B,KVH,128,NSEQ) ----------------
__global__ void k_transpose_v(const u16* __restrict__ vp, u16* __restrict__ vt) {
  size_t idx = (size_t)blockIdx.x * 256 + threadIdx.x;
  if (idx >= (size_t)BATCH * KVH * HD * NSEQ) return;
  int n = (int)(idx & (NSEQ - 1));
  int d = (int)((idx >> 11) & (HD - 1));
  int h = (int)((idx >> 18) & (KVH - 1));
  int b = (int)(idx >> 20);
  vt[idx] = vp[(size_t)(b * NSEQ + n) * QKVS + h * HD + d];
}

// ---------------- fused QKV GEMM: C(4096,3072) = [xq|xk|xv] @ [Wq|Wk|Wv]^T + bias ----------
__global__ __launch_bounds__(256) void k_gemm_qkv(const u16* __restrict__ xq, const u16* __restrict__ xk,
                                                  const u16* __restrict__ xv,
                                                  const u16* __restrict__ wq, const u16* __restrict__ wk,
                                                  const u16* __restrict__ wv,
                                                  const float* __restrict__ bq, const float* __restrict__ bk,
                                                  const float* __restrict__ bv, u16* __restrict__ C) {
  __shared__ __align__(16) u16 As[128 * 32];
  __shared__ __align__(16) u16 Bs[128 * 32];
  int tid = threadIdx.x;
  int l = tid & 63, w = tid >> 6;
  int lg = l >> 4, lr = l & 15;
  int wr = w >> 1, wc = w & 1;
  int bm = blockIdx.x, bn = blockIdx.y;

  const u16* A; const u16* B; const float* bias;
  if (bn < 16)      { A = xq; B = wq + (size_t)(bn * 128) * 2048;        bias = bq + bn * 128; }
  else if (bn < 20) { A = xk; B = wk + (size_t)((bn - 16) * 128) * 2048; bias = bk + (bn - 16) * 128; }
  else              { A = xv; B = wv + (size_t)((bn - 20) * 128) * 2048; bias = bv + (bn - 20) * 128; }

  int srow = tid >> 2;
  int scol = (tid & 3) * 16;

  const char* Ab = (const char*)A + ((size_t)(bm * 128 + srow) * 2048) * 2 + scol;
  const char* Bb = (const char*)B + ((size_t)srow * 2048) * 2 + scol;
  char* AsB = (char*)As;
  char* BsB = (char*)Bs;

  f32x4 acc[4][4] = {};
  for (int kt = 0; kt < 64; ++kt) {
    __syncthreads();
    size_t koff = (size_t)kt * 64;
    gload_lds16(Ab + koff, AsB + srow * 64 + scol);
    gload_lds16(Ab + koff + (size_t)64 * 2048 * 2, AsB + (srow + 64) * 64 + scol);
    gload_lds16(Bb + koff, BsB + srow * 64 + scol);
    gload_lds16(Bb + koff + (size_t)64 * 2048 * 2, BsB + (srow + 64) * 64 + scol);
    __syncthreads();

    v8bf af[4], bfr[4];
#pragma unroll
    for (int mi = 0; mi < 4; ++mi)
      af[mi] = *(const v8bf*)(AsB + (wr * 64 + mi * 16 + lr) * 64 + lg * 16);
#pragma unroll
    for (int ni = 0; ni < 4; ++ni)
      bfr[ni] = *(const v8bf*)(BsB + (wc * 64 + ni * 16 + lr) * 64 + lg * 16);
#pragma unroll
    for (int mi = 0; mi < 4; ++mi)
#pragma unroll
      for (int ni = 0; ni < 4; ++ni)
        acc[mi][ni] = __builtin_amdgcn_mfma_f32_16x16x32_bf16(af[mi], bfr[ni], acc[mi][ni], 0, 0, 0);
  }

#pragma unroll
  for (int mi = 0; mi < 4; ++mi)
#pragma unroll
    for (int ni = 0; ni < 4; ++ni) {
      int grow0 = bm * 128 + wr * 64 + mi * 16 + lg * 4;
      int lcol = wc * 64 + ni * 16 + lr;
      int gcol = bn * 128 + lcol;
      float bsv = bias[lcol];
#pragma unroll
      for (int r = 0; r < 4; ++r) {
        float v = acc[mi][ni][r] + bsv;
        C[(size_t)(grow0 + r) * QKVS + gcol] = f2bf(v);
      }
    }
}

// ---------------- bf16 GEMM: C(M,N) = A(M,K) @ B(N,K)^T + bias (fp32 out) ------------------
__global__ __launch_bounds__(256) void k_gemm_bt(const u16* __restrict__ A, const u16* __restrict__ B,
                                                 const float* __restrict__ bias, float* __restrict__ C,
                                                 int M, int N, int K) {
  __shared__ __align__(16) u16 As[128 * 32];
  __shared__ __align__(16) u16 Bs[128 * 32];
  int tid = threadIdx.x;
  int l = tid & 63, w = tid >> 6;
  int lg = l >> 4, lr = l & 15;
  int wr = w >> 1, wc = w & 1;
  int bm = blockIdx.x, bn = blockIdx.y;

  int srow = tid >> 2;
  int scol = (tid & 3) * 16;

  const char* Ab = (const char*)A + ((size_t)(bm * 128 + srow) * K) * 2 + scol;
  const char* Bb = (const char*)B + ((size_t)(bn * 128 + srow) * K) * 2 + scol;
  char* AsB = (char*)As;
  char* BsB = (char*)Bs;

  f32x4 acc[4][4] = {};
  int ksteps = K >> 5;
  for (int kt = 0; kt < ksteps; ++kt) {
    __syncthreads();
    size_t koff = (size_t)kt * 64;
    gload_lds16(Ab + koff, AsB + srow * 64 + scol);
    gload_lds16(Ab + koff + (size_t)64 * K * 2, AsB + (srow + 64) * 64 + scol);
    gload_lds16(Bb + koff, BsB + srow * 64 + scol);
    gload_lds16(Bb + koff + (size_t)64 * K * 2, BsB + (srow + 64) * 64 + scol);
    __syncthreads();

    v8bf af[4], bfr[4];
#pragma unroll
    for (int mi = 0; mi < 4; ++mi)
      af[mi] = *(const v8bf*)(AsB + (wr * 64 + mi * 16 + lr) * 64 + lg * 16);
#pragma unroll
    for (int ni = 0; ni < 4; ++ni)
      bfr[ni] = *(const v8bf*)(BsB + (wc * 64 + ni * 16 + lr) * 64 + lg * 16);
#pragma unroll
    for (int mi = 0; mi < 4; ++mi)
#pragma unroll
      for (int ni = 0; ni < 4; ++ni)
        acc[mi][ni] = __builtin_amdgcn_mfma_f32_16x16x32_bf16(af[mi], bfr[ni], acc[mi][ni], 0, 0, 0);
  }

#pragma unroll
  for (int mi = 0; mi < 4; ++mi)
#pragma unroll
    for (int ni = 0; ni < 4; ++ni) {
      int grow0 = bm * 128 + wr * 64 + mi * 16 + lg * 4;
      int gcol = bn * 128 + wc * 64 + ni * 16 + lr;
      float bsv = bias[gcol];
#pragma unroll
      for (int r = 0; r < 4; ++r)
        C[(size_t)(grow0 + r) * N + gcol] = acc[mi][ni][r] + bsv;
    }
}

// ---------------- flash attention v3: swapped QK^T, in-register P ----------------
// q rows stride QKVS (cols h*128..), k rows stride QKVS (region base pre-offset),
// vt: (B,KVH,128,NSEQ).  out: (B,N,2048) bf16 stride DIM_.
// K staged into LDS with row permutation psi(kv): bits b5,b43,b2,b10 -> b5,b2,b43,b10,
// so post-MFMA each lane's 16 P values are exactly the PV A-fragment (no cross-lane moves).
__global__ __launch_bounds__(256, 2) void k_attn(const u16* __restrict__ q, const u16* __restrict__ k,
                                                 const u16* __restrict__ vt, u16* __restrict__ out) {
  __shared__ __align__(16) u16 Ks[64 * 128];   // rows=psi(kv), 256B rows, XOR-swizzled
  __shared__ __align__(16) u16 Vs[128 * 64];   // rows=d, 128B rows, XOR-swizzled

  int tid = threadIdx.x;
  int l = tid & 63, w = tid >> 6;
  int lg = l >> 4, lr = l & 15;
  int h = blockIdx.y, b = blockIdx.z;
  int kvh = h >> 2;
  const float SCL2 = 0.12752551286084109f;  // (1/sqrt(128)) * log2(e)
  const float THR2 = 11.541560327111708f;   // 8 * log2(e)

  const char* kbase = (const char*)k + ((size_t)(b * NSEQ) * QKVS + kvh * HD) * 2;
  const char* vbase = (const char*)vt + ((size_t)(b * KVH + kvh) * HD) * NSEQ * 2;
  char* KsB = (char*)Ks;
  char* VsB = (char*)Vs;

  int krow0 = tid >> 4;          // 0..15 (x4 rows via i)
  int kcol = (tid & 15) * 16;    // 0..240
  int vrow0 = tid >> 3;          // 0..31 (x4 rows via i)
  int vcol = (tid & 7) * 16;     // 0..112

  v8bf kr[4], vr[4];

#define LOADKV(KT)                                                                          \
  {                                                                                         \
    _Pragma("unroll") for (int i = 0; i < 4; ++i)                                           \
        kr[i] = *(const v8bf*)(kbase + (size_t)((KT) * 64 + krow0 + i * 16) * QKVS * 2 + kcol); \
    _Pragma("unroll") for (int i = 0; i < 4; ++i)                                           \
        vr[i] = *(const v8bf*)(vbase + (size_t)(vrow0 + i * 32) * NSEQ * 2 + (size_t)(KT) * 128 + vcol); \
  }
#define WRITEKV()                                                                           \
  {                                                                                         \
    _Pragma("unroll") for (int i = 0; i < 4; ++i) {                                         \
      int kvl = krow0 + i * 16;                                                             \
      int prow = (kvl & 32) + ((kvl & 4) << 2) + ((kvl & 24) >> 1) + (kvl & 3);             \
      *(v8bf*)(KsB + prow * 256 + (kcol ^ ((prow & 7) << 4))) = kr[i];                      \
    }                                                                                       \
    _Pragma("unroll") for (int i = 0; i < 4; ++i) {                                         \
      int row = vrow0 + i * 32;                                                             \
      *(v8bf*)(VsB + row * 128 + (vcol ^ ((row & 7) << 4))) = vr[i];                        \
    }                                                                                       \
  }

  for (int pass = 0; pass < 2; ++pass) {
    int qt = pass ? (31 - blockIdx.x) : blockIdx.x;
    int q0 = qt * 64 + w * 16;

    const char* qb = (const char*)q + ((size_t)(b * NSEQ + q0 + lr) * QKVS + h * HD) * 2;
    v8bf qf[4];
#pragma unroll
    for (int kk = 0; kk < 4; ++kk) qf[kk] = *(const v8bf*)(qb + kk * 64 + lg * 16);

    f32x4 od[8] = {};
    float m2 = -INFINITY, lsum = 0.f;
    int qrow = q0 + lr;  // this lane's q-row (P ownership)

    int ktmax = qt;
    LOADKV(0);
    WRITEKV();
    __syncthreads();

    for (int kt = 0; kt <= ktmax; ++kt) {
      if (kt < ktmax) LOADKV(kt + 1);  // in flight during compute

      // S^T = K Q^T : lane owns q-col = lr; rows kv = phi(nt, lg*4+r)
      f32x4 st[4];
      __builtin_amdgcn_s_setprio(1);
#pragma unroll
      for (int nt = 0; nt < 4; ++nt) {
        f32x4 a = {};
#pragma unroll
        for (int kk = 0; kk < 4; ++kk) {
          int krow = nt * 16 + lr;
          v8bf kf = *(const v8bf*)(KsB + krow * 256 + ((kk * 64 + lg * 16) ^ ((krow & 7) << 4)));
          a = __builtin_amdgcn_mfma_f32_16x16x32_bf16(kf, qf[kk], a, 0, 0, 0);
        }
        st[nt] = a;
      }
      __builtin_amdgcn_s_setprio(0);

      // scale (exp2 domain) + causal mask + row max (in-lane 16 + xor16 + xor32)
      float mx = -1e30f;
#pragma unroll
      for (int nt = 0; nt < 4; ++nt)
#pragma unroll
        for (int r = 0; r < 4; ++r) {
          int kv = kt * 64 + (nt >> 1) * 32 + lg * 8 + ((nt & 1) << 2) + r;
          float v = st[nt][r] * SCL2;
          if (kv > qrow) v = -1e30f;
          st[nt][r] = v;
          mx = fmaxf(mx, v);
        }
      mx = fmaxf(mx, __shfl_xor(mx, 16));
      mx = fmaxf(mx, __shfl_xor(mx, 32));

      // defer-max (T13): rescale only when tile max grew past threshold
      if (!__all(mx - m2 <= THR2)) {
        float nm2 = fmaxf(m2, mx);
        float corrf = exp2f(m2 - nm2);
        m2 = nm2;
        lsum *= corrf;
#pragma unroll
        for (int r = 0; r < 4; ++r) {
          float cb = __shfl(corrf, lg * 4 + r);
#pragma unroll
          for (int dt = 0; dt < 8; ++dt) od[dt][r] *= cb;
        }
      }

      float rs = 0.f;
#pragma unroll
      for (int nt = 0; nt < 4; ++nt)
#pragma unroll
        for (int r = 0; r < 4; ++r) {
          float pv = exp2f(st[nt][r] - m2);
          st[nt][r] = pv;
          rs += pv;
        }
      rs += __shfl_xor(rs, 16);
      rs += __shfl_xor(rs, 32);
      lsum += rs;

      // pack P to bf16 pairs in-register (kv pairs are (nt, 2s),(nt, 2s+1))
      uint32_t pk[4][2];
#pragma unroll
      for (int nt = 0; nt < 4; ++nt)
#pragma unroll
        for (int s = 0; s < 2; ++s)
          pk[nt][s] = cvt_pk_bf16(st[nt][2 * s], st[nt][2 * s + 1]);

      // O += P V
      __builtin_amdgcn_s_setprio(1);
#pragma unroll
      for (int kc = 0; kc < 2; ++kc) {
        union { uint32_t u[4]; v8bf v; } pfu;
        pfu.u[0] = pk[2 * kc][0];
        pfu.u[1] = pk[2 * kc][1];
        pfu.u[2] = pk[2 * kc + 1][0];
        pfu.u[3] = pk[2 * kc + 1][1];
#pragma unroll
        for (int dt = 0; dt < 8; ++dt) {
          int vrow = dt * 16 + lr;
          v8bf vf = *(const v8bf*)(VsB + vrow * 128 + ((kc * 64 + lg * 16) ^ ((vrow & 7) << 4)));
          od[dt] = __builtin_amdgcn_mfma_f32_16x16x32_bf16(pfu.v, vf, od[dt], 0, 0, 0);
        }
      }
      __builtin_amdgcn_s_setprio(0);

      __syncthreads();              // all reads of current tile done
      if (kt < ktmax) WRITEKV();    // vmcnt wait inserted by compiler
      __syncthreads();              // new tile visible
    }

    // normalize + write (od row = q0 + lg*4 + r; lsum lives in lane lr == that row)
#pragma unroll
    for (int r = 0; r < 4; ++r) {
      float ls = __shfl(lsum, lg * 4 + r);
      float inv = 1.0f / ls;
      int qr = q0 + lg * 4 + r;
      char* ob = (char*)out + ((size_t)(b * NSEQ + qr) * DIM_ + h * HD) * 2;
#pragma unroll
      for (int dt = 0; dt < 8; ++dt)
        *(u16*)(ob + (dt * 16 + lr) * 2) = f2bf(od[dt][r] * inv);
    }
  }
#undef LOADKV
#undef WRITEKV
}

// ---------------- launch ----------------
extern "C" void kernel_launch(void* const* d_in, const int* in_sizes, int n_in,
                              void* d_out, int out_size, void* d_ws, size_t ws_size,
                              hipStream_t stream) {
  const float* query = (const float*)d_in[0];
  const float* key_ = (const float*)d_in[1];
  const float* value = (const float*)d_in[2];
  const float* Wq = (const float*)d_in[3];
  const float* bq = (const float*)d_in[4];
  const float* Wk = (const float*)d_in[5];
  const float* bk = (const float*)d_in[6];
  const float* Wv = (const float*)d_in[7];
  const float* bv = (const float*)d_in[8];
  const float* Wo = (const float*)d_in[9];
  const float* bo = (const float*)d_in[10];

  char* ws = (char*)d_ws;
  u16* wq_bf = (u16*)(ws + 0);            // 8,388,608
  u16* wk_bf = (u16*)(ws + 8388608);      // 2,097,152
  u16* wv_bf = (u16*)(ws + 10485760);     // 2,097,152
  u16* wo_bf = (u16*)(ws + 12582912);     // 8,388,608
  float* tabc = (float*)(ws + 20971520);  // 524,288
  float* tabs = (float*)(ws + 21495808);  // 524,288
  u16* xq = (u16*)(ws + 22020096);        // 16,777,216
  u16* xk = (u16*)(ws + 38797312);        // 16,777,216
  u16* xv = (u16*)(ws + 55574528);        // 16,777,216
  u16* qkvproj = (u16*)(ws + 72351744);   // 25,165,824 (total 97,517,568)
  u16* vt = xq;       // xq dead after fused QKV GEMM
  u16* attno = xk;    // xk dead after fused QKV GEMM

  k_f32_to_bf16<<<dim3(DIM_ * DIM_ / 1024), 256, 0, stream>>>(Wq, wq_bf, DIM_ * DIM_);
  k_f32_to_bf16<<<dim3(KVDIM * DIM_ / 1024), 256, 0, stream>>>(Wk, wk_bf, KVDIM * DIM_);
  k_f32_to_bf16<<<dim3(KVDIM * DIM_ / 1024), 256, 0, stream>>>(Wv, wv_bf, KVDIM * DIM_);
  k_f32_to_bf16<<<dim3(DIM_ * DIM_ / 1024), 256, 0, stream>>>(Wo, wo_bf, DIM_ * DIM_);
  k_f32_to_bf16<<<dim3(MROWS * DIM_ / 1024), 256, 0, stream>>>(query, xq, MROWS * DIM_);
  k_f32_to_bf16<<<dim3(MROWS * DIM_ / 1024), 256, 0, stream>>>(key_, xk, MROWS * DIM_);
  k_f32_to_bf16<<<dim3(MROWS * DIM_ / 1024), 256, 0, stream>>>(value, xv, MROWS * DIM_);
  k_rope_table<<<dim3(NSEQ * 64 / 256), 256, 0, stream>>>(tabc, tabs);

  k_gemm_qkv<<<dim3(MROWS / 128, QKVS / 128), 256, 0, stream>>>(xq, xk, xv, wq_bf, wk_bf, wv_bf,
                                                                bq, bk, bv, qkvproj);

  k_rope<<<dim3(MROWS * QH * 64 / 256), 256, 0, stream>>>(qkvproj, tabc, tabs, QH, QKVS);
  k_rope<<<dim3(MROWS * KVH * 64 / 256), 256, 0, stream>>>(qkvproj + 2048, tabc, tabs, KVH, QKVS);
  k_transpose_v<<<dim3((BATCH * KVH * HD * NSEQ) / 256), 256, 0, stream>>>(qkvproj + 2560, vt);

  k_attn<<<dim3(NSEQ / 128, QH, BATCH), 256, 0, stream>>>(qkvproj, qkvproj + 2048, vt, attno);

  k_gemm_bt<<<dim3(MROWS / 128, DIM_ / 128), 256, 0, stream>>>(attno, wo_bf, bo, (float*)d_out, MROWS, DIM_, DIM_);
}

// Round 5
// 248.869 us; speedup vs baseline: 2.1372x; 1.1230x over previous
//
#include <hip/hip_runtime.h>
#include <hip/hip_bf16.h>
#include <stdint.h>

typedef unsigned short u16;
typedef __bf16 v8bf __attribute__((ext_vector_type(8)));
typedef float f32x4 __attribute__((ext_vector_type(4)));

#define BATCH 2
#define NSEQ  2048
#define DIM_  2048
#define QH    16
#define KVH   4
#define HD    128
#define KVDIM 512
#define QKVS  3072
#define MROWS (BATCH*NSEQ)

__device__ __forceinline__ u16 f2bf(float f) {
  uint32_t u = __builtin_bit_cast(uint32_t, f);
  u += 0x7FFFu + ((u >> 16) & 1u);
  return (u16)(u >> 16);
}
__device__ __forceinline__ float bf2f(u16 h) {
  uint32_t u = ((uint32_t)h) << 16;
  return __builtin_bit_cast(float, u);
}
__device__ __forceinline__ uint32_t cvt_pk_bf16(float lo, float hi) {
  uint32_t r;
  asm("v_cvt_pk_bf16_f32 %0, %1, %2" : "=v"(r) : "v"(lo), "v"(hi));
  return r;
}
__device__ __forceinline__ void gload_lds16(const void* g, void* l) {
  __builtin_amdgcn_global_load_lds((const __attribute__((address_space(1))) void*)g,
                                   (__attribute__((address_space(3))) void*)l, 16, 0, 0);
}

// ---------------- fused weight converts: Wq|Wk|Wv|Wo -> bf16 ----------------
__global__ void k_conv_w(const float* __restrict__ wq, const float* __restrict__ wk,
                         const float* __restrict__ wv, const float* __restrict__ wo,
                         u16* __restrict__ oq, u16* __restrict__ ok,
                         u16* __restrict__ ov, u16* __restrict__ oo) {
  int i = (blockIdx.x * 256 + threadIdx.x) * 4;
  const float* in; u16* out; int e;
  if (i < 4194304)      { in = wq; out = oq; e = i; }
  else if (i < 5242880) { in = wk; out = ok; e = i - 4194304; }
  else if (i < 6291456) { in = wv; out = ov; e = i - 5242880; }
  else                  { in = wo; out = oo; e = i - 6291456; }
  float4 v = *(const float4*)(in + e);
  ushort4 o;
  o.x = f2bf(v.x); o.y = f2bf(v.y); o.z = f2bf(v.z); o.w = f2bf(v.w);
  *(ushort4*)(out + e) = o;
}

// ---------------- fused activation converts: query|key|value -> bf16 ----------------
__global__ void k_conv_x(const float* __restrict__ q, const float* __restrict__ k,
                         const float* __restrict__ v,
                         u16* __restrict__ oq, u16* __restrict__ ok, u16* __restrict__ ov) {
  int i = (blockIdx.x * 256 + threadIdx.x) * 4;
  int r = i >> 23;
  int e = i & ((1 << 23) - 1);
  const float* in = (r == 0) ? q : (r == 1 ? k : v);
  u16* out = (r == 0) ? oq : (r == 1 ? ok : ov);
  float4 vv = *(const float4*)(in + e);
  ushort4 o;
  o.x = f2bf(vv.x); o.y = f2bf(vv.y); o.z = f2bf(vv.z); o.w = f2bf(vv.w);
  *(ushort4*)(out + e) = o;
}

// ---------------- RoPE cos/sin table: [NSEQ][64] float2 (cos,sin) ----------------
__global__ void k_rope_table2(float2* __restrict__ tab) {
  int idx = blockIdx.x * 256 + threadIdx.x;
  if (idx < NSEQ * 64) {
    int i = idx & 63;
    float inv = powf(10000.0f, -(float)i / 64.0f);
    float ang = (float)(idx >> 6) * inv;
    tab[idx] = make_float2(cosf(ang), sinf(ang));
  }
}

// ---------------- V transpose: rows (MROWS, stride=QKVS) -> (B,KVH,128,NSEQ) ----------------
__global__ void k_transpose_v(const u16* __restrict__ vp, u16* __restrict__ vt) {
  size_t idx = (size_t)blockIdx.x * 256 + threadIdx.x;
  if (idx >= (size_t)BATCH * KVH * HD * NSEQ) return;
  int n = (int)(idx & (NSEQ - 1));
  int d = (int)((idx >> 11) & (HD - 1));
  int h = (int)((idx >> 18) & (KVH - 1));
  int b = (int)(idx >> 20);
  vt[idx] = vp[(size_t)(b * NSEQ + n) * QKVS + h * HD + d];
}

// ---------------- fused QKV GEMM (2-phase dbuf): C(4096,3072), RoPE fused for Q/K ----------
__global__ __launch_bounds__(256) void k_gemm_qkv(const u16* __restrict__ xq, const u16* __restrict__ xk,
                                                  const u16* __restrict__ xv,
                                                  const u16* __restrict__ wq, const u16* __restrict__ wk,
                                                  const u16* __restrict__ wv,
                                                  const float* __restrict__ bq, const float* __restrict__ bk,
                                                  const float* __restrict__ bv,
                                                  const float2* __restrict__ tab2, u16* __restrict__ C) {
  __shared__ __align__(16) u16 As[2][128 * 32];
  __shared__ __align__(16) u16 Bs[2][128 * 32];
  int tid = threadIdx.x;
  int l = tid & 63, w = tid >> 6;
  int lg = l >> 4, lr = l & 15;
  int wr = w >> 1, wc = w & 1;
  int bm = blockIdx.x, bn = blockIdx.y;

  const u16* A; const u16* B; const float* bias;
  if (bn < 16)      { A = xq; B = wq + (size_t)(bn * 128) * 2048;        bias = bq + bn * 128; }
  else if (bn < 20) { A = xk; B = wk + (size_t)((bn - 16) * 128) * 2048; bias = bk + (bn - 16) * 128; }
  else              { A = xv; B = wv + (size_t)((bn - 20) * 128) * 2048; bias = bv + (bn - 20) * 128; }

  int srow = tid >> 2;
  int scol = (tid & 3) * 16;

  const char* Ab = (const char*)A + ((size_t)(bm * 128 + srow) * 2048) * 2 + scol;
  const char* Bb = (const char*)B + ((size_t)srow * 2048) * 2 + scol;

#define STG(BUF, KT)                                                            \
  {                                                                             \
    size_t koff = (size_t)(KT) * 64;                                            \
    gload_lds16(Ab + koff, (char*)As[BUF] + srow * 64 + scol);                  \
    gload_lds16(Ab + koff + (size_t)64 * 2048 * 2,                              \
                (char*)As[BUF] + (srow + 64) * 64 + scol);                      \
    gload_lds16(Bb + koff, (char*)Bs[BUF] + srow * 64 + scol);                  \
    gload_lds16(Bb + koff + (size_t)64 * 2048 * 2,                              \
                (char*)Bs[BUF] + (srow + 64) * 64 + scol);                      \
  }

  f32x4 acc[4][4] = {};
  STG(0, 0);
  __syncthreads();
  for (int kt = 0; kt < 64; ++kt) {
    int cur = kt & 1;
    if (kt < 63) STG(cur ^ 1, kt + 1);   // in flight during compute
    const char* AsB = (const char*)As[cur];
    const char* BsB = (const char*)Bs[cur];
    v8bf af[4], bfr[4];
#pragma unroll
    for (int mi = 0; mi < 4; ++mi)
      af[mi] = *(const v8bf*)(AsB + (wr * 64 + mi * 16 + lr) * 64 + lg * 16);
#pragma unroll
    for (int ni = 0; ni < 4; ++ni)
      bfr[ni] = *(const v8bf*)(BsB + (wc * 64 + ni * 16 + lr) * 64 + lg * 16);
#pragma unroll
    for (int mi = 0; mi < 4; ++mi)
#pragma unroll
      for (int ni = 0; ni < 4; ++ni)
        acc[mi][ni] = __builtin_amdgcn_mfma_f32_16x16x32_bf16(af[mi], bfr[ni], acc[mi][ni], 0, 0, 0);
    __syncthreads();   // drains vmcnt: next tile has landed; old buffer free
  }
#undef STG

  bool rope = (bn < 20);
#pragma unroll
  for (int mi = 0; mi < 4; ++mi)
#pragma unroll
    for (int ni = 0; ni < 4; ++ni) {
      int grow0 = bm * 128 + wr * 64 + mi * 16 + lg * 4;
      int lcol = wc * 64 + ni * 16 + lr;
      int gcol = bn * 128 + lcol;
      float bsv = bias[lcol];
      if (rope) {
        int i2 = (gcol & 127) >> 1;
#pragma unroll
        for (int r = 0; r < 4; ++r) {
          float v = acc[mi][ni][r] + bsv;
          float pv = __shfl_xor(v, 1);
          int t = (grow0 + r) & (NSEQ - 1);
          float2 cs = tab2[t * 64 + i2];
          float y = (lr & 1) ? (pv * cs.y + v * cs.x) : (v * cs.x - pv * cs.y);
          C[(size_t)(grow0 + r) * QKVS + gcol] = f2bf(y);
        }
      } else {
#pragma unroll
        for (int r = 0; r < 4; ++r)
          C[(size_t)(grow0 + r) * QKVS + gcol] = f2bf(acc[mi][ni][r] + bsv);
      }
    }
}

// ---------------- bf16 GEMM (2-phase dbuf): C(M,N) = A(M,K) @ B(N,K)^T + bias, fp32 out ----
__global__ __launch_bounds__(256) void k_gemm_bt(const u16* __restrict__ A, const u16* __restrict__ B,
                                                 const float* __restrict__ bias, float* __restrict__ C,
                                                 int M, int N, int K) {
  __shared__ __align__(16) u16 As[2][128 * 32];
  __shared__ __align__(16) u16 Bs[2][128 * 32];
  int tid = threadIdx.x;
  int l = tid & 63, w = tid >> 6;
  int lg = l >> 4, lr = l & 15;
  int wr = w >> 1, wc = w & 1;
  int bm = blockIdx.x, bn = blockIdx.y;

  int srow = tid >> 2;
  int scol = (tid & 3) * 16;

  const char* Ab = (const char*)A + ((size_t)(bm * 128 + srow) * K) * 2 + scol;
  const char* Bb = (const char*)B + ((size_t)(bn * 128 + srow) * K) * 2 + scol;

#define STG(BUF, KT)                                                            \
  {                                                                             \
    size_t koff = (size_t)(KT) * 64;                                            \
    gload_lds16(Ab + koff, (char*)As[BUF] + srow * 64 + scol);                  \
    gload_lds16(Ab + koff + (size_t)64 * K * 2,                                 \
                (char*)As[BUF] + (srow + 64) * 64 + scol);                      \
    gload_lds16(Bb + koff, (char*)Bs[BUF] + srow * 64 + scol);                  \
    gload_lds16(Bb + koff + (size_t)64 * K * 2,                                 \
                (char*)Bs[BUF] + (srow + 64) * 64 + scol);                      \
  }

  f32x4 acc[4][4] = {};
  int ksteps = K >> 5;
  STG(0, 0);
  __syncthreads();
  for (int kt = 0; kt < ksteps; ++kt) {
    int cur = kt & 1;
    if (kt + 1 < ksteps) STG(cur ^ 1, kt + 1);
    const char* AsB = (const char*)As[cur];
    const char* BsB = (const char*)Bs[cur];
    v8bf af[4], bfr[4];
#pragma unroll
    for (int mi = 0; mi < 4; ++mi)
      af[mi] = *(const v8bf*)(AsB + (wr * 64 + mi * 16 + lr) * 64 + lg * 16);
#pragma unroll
    for (int ni = 0; ni < 4; ++ni)
      bfr[ni] = *(const v8bf*)(BsB + (wc * 64 + ni * 16 + lr) * 64 + lg * 16);
#pragma unroll
    for (int mi = 0; mi < 4; ++mi)
#pragma unroll
      for (int ni = 0; ni < 4; ++ni)
        acc[mi][ni] = __builtin_amdgcn_mfma_f32_16x16x32_bf16(af[mi], bfr[ni], acc[mi][ni], 0, 0, 0);
    __syncthreads();
  }
#undef STG

#pragma unroll
  for (int mi = 0; mi < 4; ++mi)
#pragma unroll
    for (int ni = 0; ni < 4; ++ni) {
      int grow0 = bm * 128 + wr * 64 + mi * 16 + lg * 4;
      int gcol = bn * 128 + wc * 64 + ni * 16 + lr;
      float bsv = bias[gcol];
#pragma unroll
      for (int r = 0; r < 4; ++r)
        C[(size_t)(grow0 + r) * N + gcol] = acc[mi][ni][r] + bsv;
    }
}

// ---------------- flash attention v3: swapped QK^T, in-register P (unchanged, verified) ----
__global__ __launch_bounds__(256, 2) void k_attn(const u16* __restrict__ q, const u16* __restrict__ k,
                                                 const u16* __restrict__ vt, u16* __restrict__ out) {
  __shared__ __align__(16) u16 Ks[64 * 128];   // rows=psi(kv), 256B rows, XOR-swizzled
  __shared__ __align__(16) u16 Vs[128 * 64];   // rows=d, 128B rows, XOR-swizzled

  int tid = threadIdx.x;
  int l = tid & 63, w = tid >> 6;
  int lg = l >> 4, lr = l & 15;
  int h = blockIdx.y, b = blockIdx.z;
  int kvh = h >> 2;
  const float SCL2 = 0.12752551286084109f;  // (1/sqrt(128)) * log2(e)
  const float THR2 = 11.541560327111708f;   // 8 * log2(e)

  const char* kbase = (const char*)k + ((size_t)(b * NSEQ) * QKVS + kvh * HD) * 2;
  const char* vbase = (const char*)vt + ((size_t)(b * KVH + kvh) * HD) * NSEQ * 2;
  char* KsB = (char*)Ks;
  char* VsB = (char*)Vs;

  int krow0 = tid >> 4;          // 0..15 (x4 rows via i)
  int kcol = (tid & 15) * 16;    // 0..240
  int vrow0 = tid >> 3;          // 0..31 (x4 rows via i)
  int vcol = (tid & 7) * 16;     // 0..112

  v8bf kr[4], vr[4];

#define LOADKV(KT)                                                                          \
  {                                                                                         \
    _Pragma("unroll") for (int i = 0; i < 4; ++i)                                           \
        kr[i] = *(const v8bf*)(kbase + (size_t)((KT) * 64 + krow0 + i * 16) * QKVS * 2 + kcol); \
    _Pragma("unroll") for (int i = 0; i < 4; ++i)                                           \
        vr[i] = *(const v8bf*)(vbase + (size_t)(vrow0 + i * 32) * NSEQ * 2 + (size_t)(KT) * 128 + vcol); \
  }
#define WRITEKV()                                                                           \
  {                                                                                         \
    _Pragma("unroll") for (int i = 0; i < 4; ++i) {                                         \
      int kvl = krow0 + i * 16;                                                             \
      int prow = (kvl & 32) + ((kvl & 4) << 2) + ((kvl & 24) >> 1) + (kvl & 3);             \
      *(v8bf*)(KsB + prow * 256 + (kcol ^ ((prow & 7) << 4))) = kr[i];                      \
    }                                                                                       \
    _Pragma("unroll") for (int i = 0; i < 4; ++i) {                                         \
      int row = vrow0 + i * 32;                                                             \
      *(v8bf*)(VsB + row * 128 + (vcol ^ ((row & 7) << 4))) = vr[i];                        \
    }                                                                                       \
  }

  for (int pass = 0; pass < 2; ++pass) {
    int qt = pass ? (31 - blockIdx.x) : blockIdx.x;
    int q0 = qt * 64 + w * 16;

    const char* qb = (const char*)q + ((size_t)(b * NSEQ + q0 + lr) * QKVS + h * HD) * 2;
    v8bf qf[4];
#pragma unroll
    for (int kk = 0; kk < 4; ++kk) qf[kk] = *(const v8bf*)(qb + kk * 64 + lg * 16);

    f32x4 od[8] = {};
    float m2 = -INFINITY, lsum = 0.f;
    int qrow = q0 + lr;  // this lane's q-row (P ownership)

    int ktmax = qt;
    LOADKV(0);
    WRITEKV();
    __syncthreads();

    for (int kt = 0; kt <= ktmax; ++kt) {
      if (kt < ktmax) LOADKV(kt + 1);  // in flight during compute

      // S^T = K Q^T : lane owns q-col = lr; rows kv = phi(nt, lg*4+r)
      f32x4 st[4];
      __builtin_amdgcn_s_setprio(1);
#pragma unroll
      for (int nt = 0; nt < 4; ++nt) {
        f32x4 a = {};
#pragma unroll
        for (int kk = 0; kk < 4; ++kk) {
          int krow = nt * 16 + lr;
          v8bf kf = *(const v8bf*)(KsB + krow * 256 + ((kk * 64 + lg * 16) ^ ((krow & 7) << 4)));
          a = __builtin_amdgcn_mfma_f32_16x16x32_bf16(kf, qf[kk], a, 0, 0, 0);
        }
        st[nt] = a;
      }
      __builtin_amdgcn_s_setprio(0);

      // scale (exp2 domain) + causal mask + row max (in-lane 16 + xor16 + xor32)
      float mx = -1e30f;
#pragma unroll
      for (int nt = 0; nt < 4; ++nt)
#pragma unroll
        for (int r = 0; r < 4; ++r) {
          int kv = kt * 64 + (nt >> 1) * 32 + lg * 8 + ((nt & 1) << 2) + r;
          float v = st[nt][r] * SCL2;
          if (kv > qrow) v = -1e30f;
          st[nt][r] = v;
          mx = fmaxf(mx, v);
        }
      mx = fmaxf(mx, __shfl_xor(mx, 16));
      mx = fmaxf(mx, __shfl_xor(mx, 32));

      // defer-max (T13): rescale only when tile max grew past threshold
      if (!__all(mx - m2 <= THR2)) {
        float nm2 = fmaxf(m2, mx);
        float corrf = exp2f(m2 - nm2);
        m2 = nm2;
        lsum *= corrf;
#pragma unroll
        for (int r = 0; r < 4; ++r) {
          float cb = __shfl(corrf, lg * 4 + r);
#pragma unroll
          for (int dt = 0; dt < 8; ++dt) od[dt][r] *= cb;
        }
      }

      float rs = 0.f;
#pragma unroll
      for (int nt = 0; nt < 4; ++nt)
#pragma unroll
        for (int r = 0; r < 4; ++r) {
          float pv = exp2f(st[nt][r] - m2);
          st[nt][r] = pv;
          rs += pv;
        }
      rs += __shfl_xor(rs, 16);
      rs += __shfl_xor(rs, 32);
      lsum += rs;

      // pack P to bf16 pairs in-register (kv pairs are (nt, 2s),(nt, 2s+1))
      uint32_t pk[4][2];
#pragma unroll
      for (int nt = 0; nt < 4; ++nt)
#pragma unroll
        for (int s = 0; s < 2; ++s)
          pk[nt][s] = cvt_pk_bf16(st[nt][2 * s], st[nt][2 * s + 1]);

      // O += P V
      __builtin_amdgcn_s_setprio(1);
#pragma unroll
      for (int kc = 0; kc < 2; ++kc) {
        union { uint32_t u[4]; v8bf v; } pfu;
        pfu.u[0] = pk[2 * kc][0];
        pfu.u[1] = pk[2 * kc][1];
        pfu.u[2] = pk[2 * kc + 1][0];
        pfu.u[3] = pk[2 * kc + 1][1];
#pragma unroll
        for (int dt = 0; dt < 8; ++dt) {
          int vrow = dt * 16 + lr;
          v8bf vf = *(const v8bf*)(VsB + vrow * 128 + ((kc * 64 + lg * 16) ^ ((vrow & 7) << 4)));
          od[dt] = __builtin_amdgcn_mfma_f32_16x16x32_bf16(pfu.v, vf, od[dt], 0, 0, 0);
        }
      }
      __builtin_amdgcn_s_setprio(0);

      __syncthreads();              // all reads of current tile done
      if (kt < ktmax) WRITEKV();    // vmcnt wait inserted by compiler
      __syncthreads();              // new tile visible
    }

    // normalize + write (od row = q0 + lg*4 + r; lsum lives in lane lr == that row)
#pragma unroll
    for (int r = 0; r < 4; ++r) {
      float ls = __shfl(lsum, lg * 4 + r);
      float inv = 1.0f / ls;
      int qr = q0 + lg * 4 + r;
      char* ob = (char*)out + ((size_t)(b * NSEQ + qr) * DIM_ + h * HD) * 2;
#pragma unroll
      for (int dt = 0; dt < 8; ++dt)
        *(u16*)(ob + (dt * 16 + lr) * 2) = f2bf(od[dt][r] * inv);
    }
  }
#undef LOADKV
#undef WRITEKV
}

// ---------------- launch ----------------
extern "C" void kernel_launch(void* const* d_in, const int* in_sizes, int n_in,
                              void* d_out, int out_size, void* d_ws, size_t ws_size,
                              hipStream_t stream) {
  const float* query = (const float*)d_in[0];
  const float* key_ = (const float*)d_in[1];
  const float* value = (const float*)d_in[2];
  const float* Wq = (const float*)d_in[3];
  const float* bq = (const float*)d_in[4];
  const float* Wk = (const float*)d_in[5];
  const float* bk = (const float*)d_in[6];
  const float* Wv = (const float*)d_in[7];
  const float* bv = (const float*)d_in[8];
  const float* Wo = (const float*)d_in[9];
  const float* bo = (const float*)d_in[10];

  char* ws = (char*)d_ws;
  u16* wq_bf = (u16*)(ws + 0);            // 8,388,608
  u16* wk_bf = (u16*)(ws + 8388608);      // 2,097,152
  u16* wv_bf = (u16*)(ws + 10485760);     // 2,097,152
  u16* wo_bf = (u16*)(ws + 12582912);     // 8,388,608
  float2* tab2 = (float2*)(ws + 20971520);// 1,048,576
  u16* xq = (u16*)(ws + 22020096);        // 16,777,216
  u16* xk = (u16*)(ws + 38797312);        // 16,777,216
  u16* xv = (u16*)(ws + 55574528);        // 16,777,216
  u16* qkvproj = (u16*)(ws + 72351744);   // 25,165,824 (total 97,517,568)
  u16* vt = xq;       // xq dead after fused QKV GEMM
  u16* attno = xk;    // xk dead after fused QKV GEMM

  k_conv_w<<<dim3(10240), 256, 0, stream>>>(Wq, Wk, Wv, Wo, wq_bf, wk_bf, wv_bf, wo_bf);
  k_conv_x<<<dim3(24576), 256, 0, stream>>>(query, key_, value, xq, xk, xv);
  k_rope_table2<<<dim3(NSEQ * 64 / 256), 256, 0, stream>>>(tab2);

  k_gemm_qkv<<<dim3(MROWS / 128, QKVS / 128), 256, 0, stream>>>(xq, xk, xv, wq_bf, wk_bf, wv_bf,
                                                                bq, bk, bv, tab2, qkvproj);

  k_transpose_v<<<dim3((BATCH * KVH * HD * NSEQ) / 256), 256, 0, stream>>>(qkvproj + 2560, vt);

  k_attn<<<dim3(NSEQ / 128, QH, BATCH), 256, 0, stream>>>(qkvproj, qkvproj + 2048, vt, attno);

  k_gemm_bt<<<dim3(MROWS / 128, DIM_ / 128), 256, 0, stream>>>(attno, wo_bf, bo, (float*)d_out, MROWS, DIM_, DIM_);
}